// Round 19
// baseline (88.493 us; speedup 1.0000x reference)
//
#include <hip/hip_runtime.h>
#include <hip/hip_bf16.h>
#include <cstdint>

typedef __attribute__((ext_vector_type(8))) __bf16 bf16x8;
typedef __attribute__((ext_vector_type(4))) float f32x4;
typedef unsigned short u16;
typedef unsigned int u32;

struct alignas(8) U16x4 { u16 x, y, z, w; };
struct alignas(8) U32x2 { u32 x, y; };
struct alignas(16) U32x4 { u32 x, y, z, w; };

__device__ __forceinline__ u16 f2b(float x) {
    u32 u = __builtin_bit_cast(u32, x);
    u += 0x7fffu + ((u >> 16) & 1u);   // round-to-nearest-even
    return (u16)(u >> 16);
}
__device__ __forceinline__ u32 cvtpk(float lo, float hi) {
    u32 r;
    asm("v_cvt_pk_bf16_f32 %0, %1, %2" : "=v"(r) : "v"(lo), "v"(hi));
    return r;
}
__device__ __forceinline__ float vexp2(float x) {   // raw v_exp_f32 (native 2^x)
    float r;
    asm("v_exp_f32 %0, %1" : "=v"(r) : "v"(x));
    return r;
}
__device__ __forceinline__ float blo(u32 w) { return __builtin_bit_cast(float, w << 16); }
__device__ __forceinline__ float bhi(u32 w) { return __builtin_bit_cast(float, w & 0xffff0000u); }

#define LOG2E 1.44269504088896f
#define AS3(p) (__attribute__((address_space(3))) u32*)(p)
#define AS1(p) (const __attribute__((address_space(1))) u32*)(p)

// ---------------- kernel 1: f32 -> bf16 convert (hidden + weights + link) ----
// block 7168: mask * log2e. blocks 7169+: link -> bf16, k-permuted within each
// 32-k block (k = kt*16+g*4+j -> g*8+kt*4+j) so attn reads one contiguous b128.
__global__ __launch_bounds__(256) void cvt_kernel(
    const float* __restrict__ hs,
    const float* __restrict__ wq, const float* __restrict__ wk, const float* __restrict__ wv,
    const float* __restrict__ amask, const float* __restrict__ link,
    u16* __restrict__ hsb, u16* __restrict__ wb, float* __restrict__ amask2,
    u16* __restrict__ linkb)
{
    if (blockIdx.x == 7168) {          // 4096 floats = 1024 float4 chunks
        int t = threadIdx.x;
        #pragma unroll
        for (int j = 0; j < 4; ++j) {
            float4 v = ((const float4*)amask)[t + j * 256];
            v.x *= LOG2E; v.y *= LOG2E; v.z *= LOG2E; v.w *= LOG2E;
            ((float4*)amask2)[t + j * 256] = v;
        }
        return;
    }
    if (blockIdx.x > 7168) {           // link: 4096 blocks x 256 float4 chunks
        int chunk = (blockIdx.x - 7169) * 256 + threadIdx.x;   // 0..1048575
        float4 v = ((const float4*)link)[chunk];
        int row = chunk >> 8;          // b*1024 + q
        int k4 = chunk & 255;          // float4 index within row
        int blk = k4 >> 3, k4in = k4 & 7;
        int newu = ((k4in & 3) << 1) | (k4in >> 2);   // permuted 8B unit in 32-k blk
        U16x4 r4; r4.x = f2b(v.x); r4.y = f2b(v.y); r4.z = f2b(v.z); r4.w = f2b(v.w);
        *(U16x4*)(linkb + row * 1024 + blk * 32 + newu * 4) = r4;
        return;
    }
    int i = blockIdx.x * 256 + threadIdx.x;       // float4 chunk index, exact grid
    const float4* src; u16* dst; int off;
    if (i < 1048576) { src = (const float4*)hs; dst = hsb; off = i; }
    else {
        int j = i - 1048576;                      // 3 * 262144 chunks
        int w = j >> 18;
        int o = j & 262143;
        src = (const float4*)(w == 0 ? wq : (w == 1 ? wk : wv));
        dst = wb + w * 1048576;
        off = o;
    }
    float4 v = src[off];
    U16x4 r; r.x = f2b(v.x); r.y = f2b(v.y); r.z = f2b(v.z); r.w = f2b(v.w);
    *(U16x4*)(dst + off * 4) = r;
}

// ---------------- kernel 2: QKV GEMM  C[4096,3072] = A[4096,1024] * W[3072,1024]^T
// R15-proven: BK=32 double-buffered global_load_lds, {barrier; stage(t+1);
// compute(t)} loop. Q pre-scaled by 0.125*log2(e); V written transposed. ~28 us.
__global__ __launch_bounds__(256, 3) void qkv_gemm(
    const u16* __restrict__ A, const u16* __restrict__ W,
    const float* __restrict__ bq, const float* __restrict__ bk, const float* __restrict__ bv,
    u16* __restrict__ Qo, u16* __restrict__ Ko, u16* __restrict__ Vt)
{
    __shared__ u16 As[2][128 * 32];   // 8 KB per buffer
    __shared__ u16 Bs[2][128 * 32];
    const int tid = threadIdx.x;
    const int lane = tid & 63, wid = tid >> 6;
    const int wr = (wid >> 1) * 64, wc = (wid & 1) * 64;  // wave sub-tile origin
    const int g = lane >> 4, c = lane & 15;

    int lin = blockIdx.y * 24 + blockIdx.x;
    int wg = (lin & 7) * 96 + (lin >> 3);
    const int bn = wg >> 5;      // 0..23
    const int bm = wg & 31;      // 0..31

    f32x4 acc[4][4] = {};

#define GSTAGE(bf, k0)                                                              \
    {                                                                               \
        _Pragma("unroll") for (int i = 0; i < 2; ++i) {                             \
            int chunk = i * 256 + tid;                                              \
            int row = chunk >> 2, col = (chunk & 3) * 8;                            \
            const u16* ga = A + (bm * 128 + row) * 1024 + (k0) + col;               \
            const u16* gb = W + (bn * 128 + row) * 1024 + (k0) + col;               \
            u16* la = &As[bf][0] + (i * 256 + wid * 64) * 8;                        \
            u16* lb = &Bs[bf][0] + (i * 256 + wid * 64) * 8;                        \
            __builtin_amdgcn_global_load_lds(AS1(ga), AS3(la), 16, 0, 0);           \
            __builtin_amdgcn_global_load_lds(AS1(gb), AS3(lb), 16, 0, 0);           \
        }                                                                           \
    }

    GSTAGE(0, 0);

    int cur = 0;
    for (int t = 0; t < 32; ++t) {
        __syncthreads();              // stage(t) drained (issued one phase ago)
        if (t < 31) GSTAGE(cur ^ 1, (t + 1) * 32);   // overlaps compute below
        bf16x8 af[4], bf4[4];
        #pragma unroll
        for (int i = 0; i < 4; ++i)
            af[i] = *(const bf16x8*)(&As[cur][0] + (wr + i * 16 + c) * 32 + g * 8);
        #pragma unroll
        for (int j = 0; j < 4; ++j)
            bf4[j] = *(const bf16x8*)(&Bs[cur][0] + (wc + j * 16 + c) * 32 + g * 8);
        #pragma unroll
        for (int i = 0; i < 4; ++i)
            #pragma unroll
            for (int j = 0; j < 4; ++j)
                acc[i][j] = __builtin_amdgcn_mfma_f32_16x16x32_bf16(af[i], bf4[j], acc[i][j], 0, 0, 0);
        cur ^= 1;
    }
#undef GSTAGE

    const int region = bn >> 3;                      // 0=Q 1=K 2=V
    const float* bias = region == 0 ? bq : (region == 1 ? bk : bv);
    #pragma unroll
    for (int i = 0; i < 4; ++i) {
        int m0 = bm * 128 + wr + i * 16 + g * 4;
        int b = m0 >> 10, s0 = m0 & 1023;
        #pragma unroll
        for (int j = 0; j < 4; ++j) {
            int n = (bn & 7) * 128 + wc + j * 16 + c;
            float bb = bias[n];
            int h = n >> 6, d = n & 63;
            int bh = b * 16 + h;
            if (region == 2) {
                U16x4 pk;
                pk.x = f2b(acc[i][j][0] + bb);
                pk.y = f2b(acc[i][j][1] + bb);
                pk.z = f2b(acc[i][j][2] + bb);
                pk.w = f2b(acc[i][j][3] + bb);
                *(U16x4*)(Vt + (bh * 64 + d) * 1024 + s0) = pk;
            } else if (region == 1) {
                #pragma unroll
                for (int r = 0; r < 4; ++r)
                    Ko[(bh * 1024 + s0 + r) * 64 + d] = f2b(acc[i][j][r] + bb);
            } else {
                #pragma unroll
                for (int r = 0; r < 4; ++r)   // fold 1/sqrt(D) * log2(e) into Q
                    Qo[(bh * 1024 + s0 + r) * 64 + d] = f2b((acc[i][j][r] + bb) * (0.125f * LOG2E));
            }
        }
    }
}

// ---------------- kernel 3: fused attention, post-softmax multiplicative link mask
// Round-19 = R15-proven sync structure (KVBLK=32, __syncthreads dbuf, static
// buffer 2x unroll, VALU-diet pointers, vexp2, setprio) with ONE change: link
// is bf16 and k-permuted in global memory (cvt pre-pass), so staging is one
// 16B load/thread (was two) and each lane's 8 link values read back as a
// single contiguous conflict-free ds_read_b128. LDS = K(2x4K)+V(2x4K)+
// L(2x4K)+P(4x1K) = 28 KB -> 4 blocks/CU. Bisects R18: if this passes, R18's
// failure was the counted-vmcnt sync restructure, not the bf16 link.
__global__ __launch_bounds__(256, 4) void attn_kernel(
    const u16* __restrict__ Q, const u16* __restrict__ K, const u16* __restrict__ Vt,
    const float* __restrict__ amask, const u16* __restrict__ linkb,
    float* __restrict__ out)
{
    __shared__ u16 Ks[2][32 * 64];     // 4 KB per buffer
    __shared__ u16 Vs[2][64 * 32];     // 4 KB per buffer
    __shared__ u16 Ls[2][64 * 32];     // 4 KB per buffer (link bf16, permuted)
    __shared__ u16 P[4][16 * 32];      // 1 KB per wave
    const int tid = threadIdx.x;
    const int lane = tid & 63, wid = tid >> 6;
    const int g = lane >> 4, c = lane & 15;
    const int c7 = c & 7;
    const int s2 = (c >> 1) & 3;       // 2-bit spread code for V/P

    // XCD swizzle: 1024 blocks; XCD x owns logical x*128..x*128+127.
    int hw = blockIdx.x;
    int logical = (hw & 7) * 128 + (hw >> 3);
    int b = logical >> 8;              // [0,4)
    int qt = (logical >> 4) & 15;      // [0,16) tiles of 64 q-rows
    int h = logical & 15;
    int bh = b * 16 + h;
    const int qbase = qt * 64 + wid * 16;

    const u16* Qh = Q + bh * 65536;
    const u16* Kh = K + bh * 65536;
    const u16* Vh = Vt + bh * 65536;

    bf16x8 qfx0 = *(const bf16x8*)(Qh + (qbase + c) * 64 + g * 8);
    bf16x8 qfx1 = *(const bf16x8*)(Qh + (qbase + c) * 64 + 32 + g * 8);

    float lsum = 0.f;
    f32x4 ctx[4] = {};
    u16* const Pb = &P[wid][0];

    // staging thread roles (loop-invariant); K/V sources pre-swizzled (rule
    // #21); link needs no swizzle (permutation baked into global layout).
    const int krow = tid >> 3, kcir = (tid & 7) ^ (krow & 7);
    const int vrow = tid >> 2, vcir = (tid & 3) ^ ((vrow >> 1) & 3);
    // advancing source pointers (point at the NEXT tile to stage)
    const u16* gk = Kh + krow * 64 + kcir * 8;                        // += 2048/tile
    const u16* gv = Vh + vrow * 1024 + vcir * 8;                      // += 32/tile
    const u16* gl = linkb + (size_t)b * 1048576
                    + (size_t)(qt * 64 + (tid >> 2)) * 1024 + (tid & 3) * 8;  // += 32/tile
    const float* mkP = amask + b * 1024;                              // += 32/tile

#define ISSUE_STAGE(B)                                                              \
    {                                                                               \
        __builtin_amdgcn_global_load_lds(AS1(gk), AS3(&Ks[B][0] + wid * 512), 16, 0, 0); \
        __builtin_amdgcn_global_load_lds(AS1(gv), AS3(&Vs[B][0] + wid * 512), 16, 0, 0); \
        __builtin_amdgcn_global_load_lds(AS1(gl), AS3(&Ls[B][0] + wid * 512), 16, 0, 0); \
        gk += 2048; gv += 32; gl += 32;                                             \
    }

    // one kv-tile on STATIC buffer index B; stages tile T+1 into B^1.
#define ATILE(B, T)                                                                 \
    {                                                                               \
        __syncthreads();               /* stage(T) drained (issued a phase ago) */  \
        if ((T) < 31) ISSUE_STAGE((B) ^ 1)                                          \
        bf16x8 lk8 = *(const bf16x8*)(&Ls[B][0] + (wid * 16 + c) * 32 + g * 8);     \
        U32x4 lw = __builtin_bit_cast(U32x4, lk8);                                  \
        _Pragma("unroll") for (int kt = 0; kt < 2; ++kt) {                          \
            bf16x8 kf0 = *(const bf16x8*)(&Ks[B][0] + (kt * 16 + c) * 64 + ((g)     ^ c7) * 8); \
            bf16x8 kf1 = *(const bf16x8*)(&Ks[B][0] + (kt * 16 + c) * 64 + ((4 + g) ^ c7) * 8); \
            f32x4 sc = {};                                                          \
            sc = __builtin_amdgcn_mfma_f32_16x16x32_bf16(kf0, qfx0, sc, 0, 0, 0);   \
            sc = __builtin_amdgcn_mfma_f32_16x16x32_bf16(kf1, qfx1, sc, 0, 0, 0);   \
            f32x4 m4 = *(const f32x4*)(mkP + kt * 16 + g * 4);                      \
            float e0 = vexp2(sc[0] + m4[0]);                                        \
            float e1 = vexp2(sc[1] + m4[1]);                                        \
            float e2 = vexp2(sc[2] + m4[2]);                                        \
            float e3 = vexp2(sc[3] + m4[3]);                                        \
            lsum += (e0 + e1) + (e2 + e3);                                          \
            u32 wa  = kt ? lw.z : lw.x;                                             \
            u32 wbq = kt ? lw.w : lw.y;                                             \
            U32x2 pw;                                                               \
            pw.x = cvtpk(e0 * blo(wa),  e1 * bhi(wa));                              \
            pw.y = cvtpk(e2 * blo(wbq), e3 * bhi(wbq));                             \
            *(U32x2*)(Pb + c * 32 + (((kt * 4 + g) ^ (s2 << 1)) * 4)) = pw;         \
        }                                                                           \
        __builtin_amdgcn_s_setprio(1);                                              \
        bf16x8 pf = *(const bf16x8*)(Pb + c * 32 + ((g ^ s2) * 8));                 \
        _Pragma("unroll") for (int dt = 0; dt < 4; ++dt) {                          \
            bf16x8 vf = *(const bf16x8*)(&Vs[B][0] + (dt * 16 + c) * 32 + ((g ^ s2) * 8)); \
            ctx[dt] = __builtin_amdgcn_mfma_f32_16x16x32_bf16(pf, vf, ctx[dt], 0, 0, 0); \
        }                                                                           \
        __builtin_amdgcn_s_setprio(0);                                              \
        mkP += 32;                                                                  \
    }

    ISSUE_STAGE(0)                    // prologue: tile 0 -> buffer 0

    for (int it = 0; it < 16; ++it) {
        ATILE(0, it * 2);
        ATILE(1, it * 2 + 1);
    }
#undef ATILE
#undef ISSUE_STAGE

    lsum += __shfl_xor(lsum, 16, 64);
    lsum += __shfl_xor(lsum, 32, 64);

    #pragma unroll
    for (int r = 0; r < 4; ++r) {
        float inv = 1.0f / __shfl(lsum, g * 4 + r, 16);
        int q = qbase + g * 4 + r;
        float* orow = out + (size_t)b * 1048576 + (size_t)q * 1024 + h * 64;
        #pragma unroll
        for (int dt = 0; dt < 4; ++dt)
            orow[dt * 16 + c] = ctx[dt][r] * inv;
    }
}

extern "C" void kernel_launch(void* const* d_in, const int* in_sizes, int n_in,
                              void* d_out, int out_size, void* d_ws, size_t ws_size,
                              hipStream_t stream)
{
    (void)in_sizes; (void)n_in; (void)out_size; (void)ws_size;
    const float* hs    = (const float*)d_in[0];
    const float* amask = (const float*)d_in[1];
    const float* link  = (const float*)d_in[2];
    const float* Wq    = (const float*)d_in[3];
    const float* bq    = (const float*)d_in[4];
    const float* Wk    = (const float*)d_in[5];
    const float* bk    = (const float*)d_in[6];
    const float* Wv    = (const float*)d_in[7];
    const float* bv    = (const float*)d_in[8];
    float* out = (float*)d_out;

    char* ws = (char*)d_ws;
    u16* hsb = (u16*)ws;                   // 8 MiB  [4096][1024] bf16
    u16* wb  = (u16*)(ws + (8u  << 20));   // 6 MiB  [3072][1024] bf16 (Wq|Wk|Wv)
    u16* Qb  = (u16*)(ws + (14u << 20));   // 8 MiB  [B,H,S,64]  (pre-scaled)
    u16* Kb  = (u16*)(ws + (22u << 20));   // 8 MiB  [B,H,S,64]
    u16* Vtb = (u16*)(ws + (30u << 20));   // 8 MiB  [B,H,64,S]
    float* amask2 = (float*)(ws + (38u << 20));  // 16 KB scaled mask
    u16* linkb = (u16*)(ws + (40u << 20)); // 8 MiB  [B,S,S] bf16, k-permuted

    cvt_kernel<<<11265, 256, 0, stream>>>(hs, Wq, Wk, Wv, amask, link, hsb, wb, amask2, linkb);
    qkv_gemm<<<dim3(24, 32), 256, 0, stream>>>(hsb, wb, bq, bk, bv, Qb, Kb, Vtb);
    attn_kernel<<<1024, 256, 0, stream>>>(Qb, Kb, Vtb, amask2, linkb, out);
}

// Round 20
// 86.018 us; speedup vs baseline: 1.0288x; 1.0288x over previous
//
#include <hip/hip_runtime.h>
#include <hip/hip_bf16.h>
#include <cstdint>

typedef __attribute__((ext_vector_type(8))) __bf16 bf16x8;
typedef __attribute__((ext_vector_type(4))) float f32x4;
typedef unsigned short u16;
typedef unsigned int u32;

struct alignas(8) U16x4 { u16 x, y, z, w; };
struct alignas(8) U32x2 { u32 x, y; };
struct alignas(16) U32x4 { u32 x, y, z, w; };

__device__ __forceinline__ u16 f2b(float x) {
    u32 u = __builtin_bit_cast(u32, x);
    u += 0x7fffu + ((u >> 16) & 1u);   // round-to-nearest-even
    return (u16)(u >> 16);
}
__device__ __forceinline__ u32 cvtpk(float lo, float hi) {
    u32 r;
    asm("v_cvt_pk_bf16_f32 %0, %1, %2" : "=v"(r) : "v"(lo), "v"(hi));
    return r;
}
__device__ __forceinline__ float vexp2(float x) {   // raw v_exp_f32 (native 2^x)
    float r;
    asm("v_exp_f32 %0, %1" : "=v"(r) : "v"(x));
    return r;
}
__device__ __forceinline__ float blo(u32 w) { return __builtin_bit_cast(float, w << 16); }
__device__ __forceinline__ float bhi(u32 w) { return __builtin_bit_cast(float, w & 0xffff0000u); }

#define LOG2E 1.44269504088896f
#define AS3(p) (__attribute__((address_space(3))) u32*)(p)
#define AS1(p) (const __attribute__((address_space(1))) u32*)(p)

// ---------------- kernel 1: f32 -> bf16 convert (hidden + weights + mask) ----
__global__ __launch_bounds__(256) void cvt_kernel(
    const float* __restrict__ hs,
    const float* __restrict__ wq, const float* __restrict__ wk, const float* __restrict__ wv,
    const float* __restrict__ amask,
    u16* __restrict__ hsb, u16* __restrict__ wb, float* __restrict__ amask2)
{
    if (blockIdx.x == 7168) {          // 4096 floats = 1024 float4 chunks
        int t = threadIdx.x;
        #pragma unroll
        for (int j = 0; j < 4; ++j) {
            float4 v = ((const float4*)amask)[t + j * 256];
            v.x *= LOG2E; v.y *= LOG2E; v.z *= LOG2E; v.w *= LOG2E;
            ((float4*)amask2)[t + j * 256] = v;
        }
        return;
    }
    int i = blockIdx.x * 256 + threadIdx.x;       // float4 chunk index, exact grid
    const float4* src; u16* dst; int off;
    if (i < 1048576) { src = (const float4*)hs; dst = hsb; off = i; }
    else {
        int j = i - 1048576;                      // 3 * 262144 chunks
        int w = j >> 18;
        int o = j & 262143;
        src = (const float4*)(w == 0 ? wq : (w == 1 ? wk : wv));
        dst = wb + w * 1048576;
        off = o;
    }
    float4 v = src[off];
    U16x4 r; r.x = f2b(v.x); r.y = f2b(v.y); r.z = f2b(v.z); r.w = f2b(v.w);
    *(U16x4*)(dst + off * 4) = r;
}

// ---------------- kernel 2: QKV GEMM + link conversion (fused launch) --------
// Blocks 0..767: BK=32 double-buffered global_load_lds GEMM (R15-proven).
// Blocks 768..4863: link f32 -> bf16, k-permuted within each 32-k block
// (k = kt*16+g*4+j -> g*8+kt*4+j). The conversion's 24 MB of pure-memory
// traffic overlaps the GEMM's dispatch window instead of serializing as its
// own ~9 us pass (R19). attn (sole consumer of linkb) launches after.
__global__ __launch_bounds__(256, 3) void qkv_gemm(
    const u16* __restrict__ A, const u16* __restrict__ W,
    const float* __restrict__ bq, const float* __restrict__ bk, const float* __restrict__ bv,
    const float* __restrict__ linkf, u16* __restrict__ linkb,
    u16* __restrict__ Qo, u16* __restrict__ Ko, u16* __restrict__ Vt)
{
    __shared__ u16 As[2][128 * 32];   // 8 KB per buffer
    __shared__ u16 Bs[2][128 * 32];
    const int tid = threadIdx.x;

    if (blockIdx.x >= 768) {           // ---- link conversion path ----
        int chunk = (blockIdx.x - 768) * 256 + tid;            // 0..1048575
        float4 v = ((const float4*)linkf)[chunk];
        int row = chunk >> 8;          // b*1024 + q
        int k4 = chunk & 255;          // float4 index within row
        int blk = k4 >> 3, k4in = k4 & 7;
        int newu = ((k4in & 3) << 1) | (k4in >> 2);   // permuted 8B unit in 32-k blk
        U16x4 r4; r4.x = f2b(v.x); r4.y = f2b(v.y); r4.z = f2b(v.z); r4.w = f2b(v.w);
        *(U16x4*)(linkb + row * 1024 + blk * 32 + newu * 4) = r4;
        return;
    }

    const int lane = tid & 63, wid = tid >> 6;
    const int wr = (wid >> 1) * 64, wc = (wid & 1) * 64;  // wave sub-tile origin
    const int g = lane >> 4, c = lane & 15;

    int lin = blockIdx.x;
    int wg = (lin & 7) * 96 + (lin >> 3);
    const int bn = wg >> 5;      // 0..23
    const int bm = wg & 31;      // 0..31

    f32x4 acc[4][4] = {};

#define GSTAGE(bf, k0)                                                              \
    {                                                                               \
        _Pragma("unroll") for (int i = 0; i < 2; ++i) {                             \
            int chunk = i * 256 + tid;                                              \
            int row = chunk >> 2, col = (chunk & 3) * 8;                            \
            const u16* ga = A + (bm * 128 + row) * 1024 + (k0) + col;               \
            const u16* gb = W + (bn * 128 + row) * 1024 + (k0) + col;               \
            u16* la = &As[bf][0] + (i * 256 + wid * 64) * 8;                        \
            u16* lb = &Bs[bf][0] + (i * 256 + wid * 64) * 8;                        \
            __builtin_amdgcn_global_load_lds(AS1(ga), AS3(la), 16, 0, 0);           \
            __builtin_amdgcn_global_load_lds(AS1(gb), AS3(lb), 16, 0, 0);           \
        }                                                                           \
    }

    GSTAGE(0, 0);

    int cur = 0;
    for (int t = 0; t < 32; ++t) {
        __syncthreads();              // stage(t) drained (issued one phase ago)
        if (t < 31) GSTAGE(cur ^ 1, (t + 1) * 32);   // overlaps compute below
        bf16x8 af[4], bf4[4];
        #pragma unroll
        for (int i = 0; i < 4; ++i)
            af[i] = *(const bf16x8*)(&As[cur][0] + (wr + i * 16 + c) * 32 + g * 8);
        #pragma unroll
        for (int j = 0; j < 4; ++j)
            bf4[j] = *(const bf16x8*)(&Bs[cur][0] + (wc + j * 16 + c) * 32 + g * 8);
        #pragma unroll
        for (int i = 0; i < 4; ++i)
            #pragma unroll
            for (int j = 0; j < 4; ++j)
                acc[i][j] = __builtin_amdgcn_mfma_f32_16x16x32_bf16(af[i], bf4[j], acc[i][j], 0, 0, 0);
        cur ^= 1;
    }
#undef GSTAGE

    const int region = bn >> 3;                      // 0=Q 1=K 2=V
    const float* bias = region == 0 ? bq : (region == 1 ? bk : bv);
    #pragma unroll
    for (int i = 0; i < 4; ++i) {
        int m0 = bm * 128 + wr + i * 16 + g * 4;
        int b = m0 >> 10, s0 = m0 & 1023;
        #pragma unroll
        for (int j = 0; j < 4; ++j) {
            int n = (bn & 7) * 128 + wc + j * 16 + c;
            float bb = bias[n];
            int h = n >> 6, d = n & 63;
            int bh = b * 16 + h;
            if (region == 2) {
                U16x4 pk;
                pk.x = f2b(acc[i][j][0] + bb);
                pk.y = f2b(acc[i][j][1] + bb);
                pk.z = f2b(acc[i][j][2] + bb);
                pk.w = f2b(acc[i][j][3] + bb);
                *(U16x4*)(Vt + (bh * 64 + d) * 1024 + s0) = pk;
            } else if (region == 1) {
                #pragma unroll
                for (int r = 0; r < 4; ++r)
                    Ko[(bh * 1024 + s0 + r) * 64 + d] = f2b(acc[i][j][r] + bb);
            } else {
                #pragma unroll
                for (int r = 0; r < 4; ++r)   // fold 1/sqrt(D) * log2(e) into Q
                    Qo[(bh * 1024 + s0 + r) * 64 + d] = f2b((acc[i][j][r] + bb) * (0.125f * LOG2E));
            }
        }
    }
}

// ---------------- kernel 3: fused attention, post-softmax multiplicative link mask
// Round-20 = R19 (43.2 us, passing) + Ls BANK SWIZZLE: stage source unit
// ^= (tid>>3)&3 (dest stays linear for global_load_lds), read at unit g^s2.
// Derivation: read byte = row*64 + (g^s2)*16, s2=(c>>1)&3 -> each 8-lane group
// covers all 32 banks exactly (was 4-way: +524K conflict cycles in R19).
// LDS = K(2x4K)+V(2x4K)+L(2x4K)+P(4x1K) = 28 KB -> 4 blocks/CU.
__global__ __launch_bounds__(256, 4) void attn_kernel(
    const u16* __restrict__ Q, const u16* __restrict__ K, const u16* __restrict__ Vt,
    const float* __restrict__ amask, const u16* __restrict__ linkb,
    float* __restrict__ out)
{
    __shared__ u16 Ks[2][32 * 64];     // 4 KB per buffer
    __shared__ u16 Vs[2][64 * 32];     // 4 KB per buffer
    __shared__ u16 Ls[2][64 * 32];     // 4 KB per buffer (link bf16, permuted)
    __shared__ u16 P[4][16 * 32];      // 1 KB per wave
    const int tid = threadIdx.x;
    const int lane = tid & 63, wid = tid >> 6;
    const int g = lane >> 4, c = lane & 15;
    const int c7 = c & 7;
    const int s2 = (c >> 1) & 3;       // 2-bit spread code for V/P/L

    // XCD swizzle: 1024 blocks; XCD x owns logical x*128..x*128+127.
    int hw = blockIdx.x;
    int logical = (hw & 7) * 128 + (hw >> 3);
    int b = logical >> 8;              // [0,4)
    int qt = (logical >> 4) & 15;      // [0,16) tiles of 64 q-rows
    int h = logical & 15;
    int bh = b * 16 + h;
    const int qbase = qt * 64 + wid * 16;

    const u16* Qh = Q + bh * 65536;
    const u16* Kh = K + bh * 65536;
    const u16* Vh = Vt + bh * 65536;

    bf16x8 qfx0 = *(const bf16x8*)(Qh + (qbase + c) * 64 + g * 8);
    bf16x8 qfx1 = *(const bf16x8*)(Qh + (qbase + c) * 64 + 32 + g * 8);

    float lsum = 0.f;
    f32x4 ctx[4] = {};
    u16* const Pb = &P[wid][0];

    // staging thread roles (loop-invariant); K/V/L sources pre-swizzled (rule #21)
    const int krow = tid >> 3, kcir = (tid & 7) ^ (krow & 7);
    const int vrow = tid >> 2, vcir = (tid & 3) ^ ((vrow >> 1) & 3);
    const int lcir = (tid & 3) ^ ((tid >> 3) & 3);   // Ls bank swizzle (row=tid>>2)
    // advancing source pointers (point at the NEXT tile to stage)
    const u16* gk = Kh + krow * 64 + kcir * 8;                        // += 2048/tile
    const u16* gv = Vh + vrow * 1024 + vcir * 8;                      // += 32/tile
    const u16* gl = linkb + (size_t)b * 1048576
                    + (size_t)(qt * 64 + (tid >> 2)) * 1024 + lcir * 8;   // += 32/tile
    const float* mkP = amask + b * 1024;                              // += 32/tile

#define ISSUE_STAGE(B)                                                              \
    {                                                                               \
        __builtin_amdgcn_global_load_lds(AS1(gk), AS3(&Ks[B][0] + wid * 512), 16, 0, 0); \
        __builtin_amdgcn_global_load_lds(AS1(gv), AS3(&Vs[B][0] + wid * 512), 16, 0, 0); \
        __builtin_amdgcn_global_load_lds(AS1(gl), AS3(&Ls[B][0] + wid * 512), 16, 0, 0); \
        gk += 2048; gv += 32; gl += 32;                                             \
    }

    // one kv-tile on STATIC buffer index B; stages tile T+1 into B^1.
#define ATILE(B, T)                                                                 \
    {                                                                               \
        __syncthreads();               /* stage(T) drained (issued a phase ago) */  \
        if ((T) < 31) ISSUE_STAGE((B) ^ 1)                                          \
        bf16x8 lk8 = *(const bf16x8*)(&Ls[B][0] + (wid * 16 + c) * 32 + ((g ^ s2) * 8)); \
        U32x4 lw = __builtin_bit_cast(U32x4, lk8);                                  \
        _Pragma("unroll") for (int kt = 0; kt < 2; ++kt) {                          \
            bf16x8 kf0 = *(const bf16x8*)(&Ks[B][0] + (kt * 16 + c) * 64 + ((g)     ^ c7) * 8); \
            bf16x8 kf1 = *(const bf16x8*)(&Ks[B][0] + (kt * 16 + c) * 64 + ((4 + g) ^ c7) * 8); \
            f32x4 sc = {};                                                          \
            sc = __builtin_amdgcn_mfma_f32_16x16x32_bf16(kf0, qfx0, sc, 0, 0, 0);   \
            sc = __builtin_amdgcn_mfma_f32_16x16x32_bf16(kf1, qfx1, sc, 0, 0, 0);   \
            f32x4 m4 = *(const f32x4*)(mkP + kt * 16 + g * 4);                      \
            float e0 = vexp2(sc[0] + m4[0]);                                        \
            float e1 = vexp2(sc[1] + m4[1]);                                        \
            float e2 = vexp2(sc[2] + m4[2]);                                        \
            float e3 = vexp2(sc[3] + m4[3]);                                        \
            lsum += (e0 + e1) + (e2 + e3);                                          \
            u32 wa  = kt ? lw.z : lw.x;                                             \
            u32 wbq = kt ? lw.w : lw.y;                                             \
            U32x2 pw;                                                               \
            pw.x = cvtpk(e0 * blo(wa),  e1 * bhi(wa));                              \
            pw.y = cvtpk(e2 * blo(wbq), e3 * bhi(wbq));                             \
            *(U32x2*)(Pb + c * 32 + (((kt * 4 + g) ^ (s2 << 1)) * 4)) = pw;         \
        }                                                                           \
        __builtin_amdgcn_s_setprio(1);                                              \
        bf16x8 pf = *(const bf16x8*)(Pb + c * 32 + ((g ^ s2) * 8));                 \
        _Pragma("unroll") for (int dt = 0; dt < 4; ++dt) {                          \
            bf16x8 vf = *(const bf16x8*)(&Vs[B][0] + (dt * 16 + c) * 32 + ((g ^ s2) * 8)); \
            ctx[dt] = __builtin_amdgcn_mfma_f32_16x16x32_bf16(pf, vf, ctx[dt], 0, 0, 0); \
        }                                                                           \
        __builtin_amdgcn_s_setprio(0);                                              \
        mkP += 32;                                                                  \
    }

    ISSUE_STAGE(0)                    // prologue: tile 0 -> buffer 0

    for (int it = 0; it < 16; ++it) {
        ATILE(0, it * 2);
        ATILE(1, it * 2 + 1);
    }
#undef ATILE
#undef ISSUE_STAGE

    lsum += __shfl_xor(lsum, 16, 64);
    lsum += __shfl_xor(lsum, 32, 64);

    #pragma unroll
    for (int r = 0; r < 4; ++r) {
        float inv = 1.0f / __shfl(lsum, g * 4 + r, 16);
        int q = qbase + g * 4 + r;
        float* orow = out + (size_t)b * 1048576 + (size_t)q * 1024 + h * 64;
        #pragma unroll
        for (int dt = 0; dt < 4; ++dt)
            orow[dt * 16 + c] = ctx[dt][r] * inv;
    }
}

extern "C" void kernel_launch(void* const* d_in, const int* in_sizes, int n_in,
                              void* d_out, int out_size, void* d_ws, size_t ws_size,
                              hipStream_t stream)
{
    (void)in_sizes; (void)n_in; (void)out_size; (void)ws_size;
    const float* hs    = (const float*)d_in[0];
    const float* amask = (const float*)d_in[1];
    const float* link  = (const float*)d_in[2];
    const float* Wq    = (const float*)d_in[3];
    const float* bq    = (const float*)d_in[4];
    const float* Wk    = (const float*)d_in[5];
    const float* bk    = (const float*)d_in[6];
    const float* Wv    = (const float*)d_in[7];
    const float* bv    = (const float*)d_in[8];
    float* out = (float*)d_out;

    char* ws = (char*)d_ws;
    u16* hsb = (u16*)ws;                   // 8 MiB  [4096][1024] bf16
    u16* wb  = (u16*)(ws + (8u  << 20));   // 6 MiB  [3072][1024] bf16 (Wq|Wk|Wv)
    u16* Qb  = (u16*)(ws + (14u << 20));   // 8 MiB  [B,H,S,64]  (pre-scaled)
    u16* Kb  = (u16*)(ws + (22u << 20));   // 8 MiB  [B,H,S,64]
    u16* Vtb = (u16*)(ws + (30u << 20));   // 8 MiB  [B,H,64,S]
    float* amask2 = (float*)(ws + (38u << 20));  // 16 KB scaled mask
    u16* linkb = (u16*)(ws + (40u << 20)); // 8 MiB  [B,S,S] bf16, k-permuted

    cvt_kernel<<<7169, 256, 0, stream>>>(hs, Wq, Wk, Wv, amask, hsb, wb, amask2);
    qkv_gemm<<<4864, 256, 0, stream>>>(hsb, wb, bq, bk, bv, link, linkb, Qb, Kb, Vtb);
    attn_kernel<<<1024, 256, 0, stream>>>(Qb, Kb, Vtb, amask2, linkb, out);
}